// Round 2
// baseline (390.928 us; speedup 1.0000x reference)
//
#include <hip/hip_runtime.h>
#include <hip/hip_bf16.h>
#include <cstdint>
#include <cstddef>

#define VOCAB 50000
#define DIM 128
#define BATCH 4096
#define CTX 10
#define NGROUPS 3125   // VOCAB/16
#define NVB 98         // ceil(NGROUPS/32): vocab blocks of 512 rows (last partial)
#define NBC 8          // batch chunks
#define BCH 512        // batch rows per block
#define ITER 32        // BCH/16

typedef short bf16x8 __attribute__((ext_vector_type(8)));
typedef float f32x4  __attribute__((ext_vector_type(4)));

// workspace layout (bytes) — total 15,470,592 (< round-1's 15.96 MB, proven fit)
#define WS_POOLED 0u          // 4096*128*2   = 1,048,576
#define WS_WB     1048576u    // 50000*128*2  = 12,800,000
#define WS_PART   13848576u   // 98*4096*4    = 1,605,632
#define WS_LSE    15454208u   // 4096*4       = 16,384

// ---------------- pool: pooled[b][d] = mean_t emb[ctx[b][t]][d]  (bf16 out)
__global__ __launch_bounds__(256) void pool_kernel(
    const int* __restrict__ ctx, const float* __restrict__ emb,
    __hip_bfloat16* __restrict__ pooled) {
  int idx = blockIdx.x * 256 + threadIdx.x;
  int b = idx >> 7, d = idx & 127;
  const int* cb = ctx + b * CTX;
  float s = 0.f;
#pragma unroll
  for (int t = 0; t < CTX; ++t) s += emb[(size_t)cb[t] * DIM + d];
  pooled[idx] = __float2bfloat16(s * 0.1f);
}

// ---------------- convert W fp32 -> bf16
__global__ __launch_bounds__(256) void convw_kernel(
    const float* __restrict__ W, __hip_bfloat16* __restrict__ Wb) {
  int idx = blockIdx.x * 256 + threadIdx.x;
  float4 v = reinterpret_cast<const float4*>(W)[idx];
  __hip_bfloat16 o[4];
  o[0] = __float2bfloat16(v.x); o[1] = __float2bfloat16(v.y);
  o[2] = __float2bfloat16(v.z); o[3] = __float2bfloat16(v.w);
  reinterpret_cast<ushort4*>(Wb)[idx] = *reinterpret_cast<ushort4*>(o);
}

__device__ __forceinline__ void loadB(bf16x8 (&B)[4], const __hip_bfloat16* base) {
#pragma unroll
  for (int ks = 0; ks < 4; ++ks)
    B[ks] = *reinterpret_cast<const bf16x8*>(base + ks * 32);
}

// ---------------- pass1: part[vb][b] = sum over this vocab-block of exp(logit)
__global__ __launch_bounds__(256, 2) void pass1_kernel(
    const __hip_bfloat16* __restrict__ pooled,
    const __hip_bfloat16* __restrict__ Wb,
    float* __restrict__ part) {
  __shared__ float smem[4][BCH];   // 8 KB
  int bc = blockIdx.x & 7;
  int vb = blockIdx.x >> 3;
  int wave = threadIdx.x >> 6, lane = threadIdx.x & 63;
  int lr = lane & 15, lk = lane >> 4;
  int bbase = bc * BCH;
  int g0 = vb * 32 + wave * 8;
  int nvg = min(8, NGROUPS - g0);

  for (int i = threadIdx.x; i < 4 * BCH; i += 256) (&smem[0][0])[i] = 0.f;
  __syncthreads();

  auto run = [&](int NV) {
    // A-fragments: W rows, held across the whole batch stream
    bf16x8 Afr[8][4];
#pragma unroll
    for (int vg = 0; vg < 8; ++vg)
      if (vg < NV) {
        const __hip_bfloat16* Ap = Wb + (size_t)((g0 + vg) * 16 + lr) * DIM + lk * 8;
#pragma unroll
        for (int ks = 0; ks < 4; ++ks)
          Afr[vg][ks] = *reinterpret_cast<const bf16x8*>(Ap + ks * 32);
      }

    const __hip_bfloat16* Bbase = pooled + (size_t)(bbase + lr) * DIM + lk * 8;
    bf16x8 Ba[4], Bb[4];
    loadB(Ba, Bbase);

    auto computeS = [&](bf16x8 (&B)[4], int it) {
      float s = 0.f;
#pragma unroll
      for (int vg = 0; vg < 8; ++vg)
        if (vg < NV) {
          f32x4 acc = {0.f, 0.f, 0.f, 0.f};
#pragma unroll
          for (int ks = 0; ks < 4; ++ks)
            acc = __builtin_amdgcn_mfma_f32_16x16x32_bf16(Afr[vg][ks], B[ks], acc, 0, 0, 0);
#pragma unroll
          for (int i2 = 0; i2 < 4; ++i2) s += __expf(acc[i2]);
        }
      s += __shfl_xor(s, 16, 64);
      s += __shfl_xor(s, 32, 64);
      if (lk == 0) smem[wave][it * 16 + lr] = s;
    };

    for (int it = 0; it < ITER; it += 2) {
      loadB(Bb, Bbase + (it + 1) * 16 * DIM);
      computeS(Ba, it);
      int itn = (it + 2 < ITER) ? (it + 2) : (ITER - 1);
      loadB(Ba, Bbase + itn * 16 * DIM);
      computeS(Bb, it + 1);
    }
  };
  if (nvg == 8) run(8);
  else if (nvg > 0) run(nvg);

  __syncthreads();
  for (int c = threadIdx.x; c < BCH; c += 256) {
    float v = smem[0][c] + smem[1][c] + smem[2][c] + smem[3][c];
    part[(size_t)vb * BATCH + bbase + c] = v;
  }
}

// ---------------- reduce: lse[b] = log(sum_vb part[vb][b])
__global__ __launch_bounds__(256) void reduce_kernel(
    const float* __restrict__ part, float* __restrict__ lse) {
  int b = blockIdx.x * 256 + threadIdx.x;
  float s = 0.f;
  for (int vb = 0; vb < NVB; ++vb) s += part[(size_t)vb * BATCH + b];
  lse[b] = __logf(s);
}

// ---------------- pass2: out[b][v] = logit - lse[b]   (float4 nontemporal)
__global__ __launch_bounds__(256, 2) void pass2_kernel(
    const __hip_bfloat16* __restrict__ pooled,
    const __hip_bfloat16* __restrict__ Wb,
    const float* __restrict__ lse, float* __restrict__ out) {
  int bc = blockIdx.x & 7;
  int vb = blockIdx.x >> 3;
  int wave = threadIdx.x >> 6, lane = threadIdx.x & 63;
  int lr = lane & 15, lk = lane >> 4;
  int bbase = bc * BCH;
  int g0 = vb * 32 + wave * 8;
  int nvg = min(8, NGROUPS - g0);
  if (nvg <= 0) return;   // no barriers below — safe

  auto run = [&](int NV) {
    bf16x8 Afr[8][4];
#pragma unroll
    for (int vg = 0; vg < 8; ++vg)
      if (vg < NV) {
        const __hip_bfloat16* Ap = Wb + (size_t)((g0 + vg) * 16 + lr) * DIM + lk * 8;
#pragma unroll
        for (int ks = 0; ks < 4; ++ks)
          Afr[vg][ks] = *reinterpret_cast<const bf16x8*>(Ap + ks * 32);
      }

    const __hip_bfloat16* Bbase = pooled + (size_t)(bbase + lr) * DIM + lk * 8;
    bf16x8 Ba[4], Bb[4];
    float la, lb;
    loadB(Ba, Bbase);
    la = lse[bbase + lr];

    auto computeStore = [&](bf16x8 (&B)[4], float lv, int it) {
#pragma unroll
      for (int vg = 0; vg < 8; ++vg)
        if (vg < NV) {
          f32x4 acc = {0.f, 0.f, 0.f, 0.f};
#pragma unroll
          for (int ks = 0; ks < 4; ++ks)
            acc = __builtin_amdgcn_mfma_f32_16x16x32_bf16(Afr[vg][ks], B[ks], acc, 0, 0, 0);
          f32x4 o = acc - lv;
          size_t off = (size_t)(bbase + it * 16 + lr) * VOCAB
                     + (size_t)(g0 + vg) * 16 + lk * 4;
          __builtin_nontemporal_store(o, reinterpret_cast<f32x4*>(out + off));
        }
    };

    for (int it = 0; it < ITER; it += 2) {
      loadB(Bb, Bbase + (it + 1) * 16 * DIM);
      lb = lse[bbase + (it + 1) * 16 + lr];
      computeStore(Ba, la, it);
      int itn = (it + 2 < ITER) ? (it + 2) : (ITER - 1);
      loadB(Ba, Bbase + itn * 16 * DIM);
      la = lse[bbase + itn * 16 + lr];
      computeStore(Bb, lb, it + 1);
    }
  };
  if (nvg == 8) run(8);
  else run(nvg);
}

extern "C" void kernel_launch(void* const* d_in, const int* in_sizes, int n_in,
                              void* d_out, int out_size, void* d_ws, size_t ws_size,
                              hipStream_t stream) {
  const int* ctx = (const int*)d_in[0];
  const float* emb = (const float*)d_in[1];
  const float* W = (const float*)d_in[2];
  float* out = (float*)d_out;

  char* ws = (char*)d_ws;
  __hip_bfloat16* pooled = (__hip_bfloat16*)(ws + WS_POOLED);
  __hip_bfloat16* Wb = (__hip_bfloat16*)(ws + WS_WB);
  float* part = (float*)(ws + WS_PART);
  float* lse = (float*)(ws + WS_LSE);

  pool_kernel<<<(BATCH * DIM) / 256, 256, 0, stream>>>(ctx, emb, pooled);
  convw_kernel<<<(VOCAB * DIM) / (256 * 4), 256, 0, stream>>>(W, Wb);
  pass1_kernel<<<NVB * NBC, 256, 0, stream>>>(pooled, Wb, part);
  reduce_kernel<<<BATCH / 256, 256, 0, stream>>>(part, lse);
  pass2_kernel<<<NVB * NBC, 256, 0, stream>>>(pooled, Wb, lse, out);
}